// Round 6
// baseline (4295.304 us; speedup 1.0000x reference)
//
#include <hip/hip_runtime.h>

// Problem: B=64, T=1024, D=512, F=512, all fp32.
// out[b,t,:] = h_t = tanh(x_t @ W_ih + bias + h_{t-1} @ W_hh)
//
// K1: x_proj GEMM [65536,512]@[512,512]+bias -> d_out (xp buffer, overwritten
//     in-place by the scan; each slot read exactly once before overwrite).
// K2: persistent scan, 256 blocks x 256 threads, group = 16 blocks (4 batch rows).
//     Exchange: 8-byte self-validating packets {lo32=float bits, hi32=step tag}
//     via relaxed agent-scope 8B atomics (MALL coherence point, R2-verified).
//     THIS ROUND (mechanism: keep the exchange MALL-resident, stop congesting it):
//     R4 counters showed hbuf packets being EVICTED to HBM (WRITE_SIZE had the
//     full 268MB of packet traffic; FETCH_SIZE had ~150MB of poll loads fetched
//     back from HBM) because the scan streams ~270MB of cached xp-loads +
//     out-stores through MALL, plus ~13TB/s of continuous 8-load polling.
//     (a) NON-TEMPORAL xp loads and out stores (and K1 C-stores): streaming
//         traffic no longer pollutes MALL -> hbuf stays resident -> exchange
//         round trips are MALL-latency, not HBM-latency.
//         (R5 fix: nontemporal builtin rejects HIP_vector_type* -- use a
//          native ext_vector_type(4) float alias for the 16B C-stores.)
//     (b) SENTINEL polling: spin on ONE packet per thread (row j&3, col colp),
//         then the full 8-load verify loop (verify alone carries correctness;
//         sentinel is a filter). Poll fabric traffic cut 8x.
//     Everything else unchanged from R4 (barrier-free same-half-wave staging,
//     xp after poll, parity-double-buffered red, 1 barrier/step, waves 0-1
//     finalize). Wait-graph remains a DAG over (block,t); all 256 blocks
//     co-resident (VGPR ~100, LDS 16KB) -> spins can't deadlock.

#define RNN_B 64
#define RNN_T 1024
#define RNN_D 512
#define RNN_F 512

typedef float floatx4 __attribute__((ext_vector_type(4)));

// ---------------------------------------------------------------------------
// Kernel 1: x_proj = X @ W_ih + bias.  M=65536, N=512, K=512.
// (unchanged except non-temporal C-stores)
// ---------------------------------------------------------------------------
__global__ __launch_bounds__(256) void xproj_gemm(
    const float* __restrict__ A,     // [65536, 512]
    const float* __restrict__ W,     // [512, 512]
    const float* __restrict__ bias,  // [512]
    float* __restrict__ C)           // [65536, 512]
{
    __shared__ float As[16][132];
    __shared__ float Bs[16][132];

    const int tid = threadIdx.x;
    const int bid = blockIdx.x;
    const int mt = bid >> 2;
    const int nt = bid & 3;
    const size_t M0 = (size_t)mt * 128;
    const int N0 = nt * 128;

    const int tm = tid >> 4;
    const int tn = tid & 15;

    const int ar = tid >> 2;
    const int ac = (tid & 3) * 4;
    const int br = tid >> 5;
    const int bc = (tid & 31) * 4;

    float acc[8][8];
    #pragma unroll
    for (int i = 0; i < 8; ++i)
        #pragma unroll
        for (int jx = 0; jx < 8; ++jx) acc[i][jx] = 0.f;

    float bv[8];
    #pragma unroll
    for (int i = 0; i < 8; ++i) bv[i] = bias[N0 + tn * 8 + i];

    for (int k0 = 0; k0 < 512; k0 += 16) {
        float4 a0 = *(const float4*)(A + (M0 + ar) * 512 + k0 + ac);
        float4 a1 = *(const float4*)(A + (M0 + ar + 64) * 512 + k0 + ac);
        float4 b0 = *(const float4*)(W + (size_t)(k0 + br) * 512 + N0 + bc);
        float4 b1 = *(const float4*)(W + (size_t)(k0 + br + 8) * 512 + N0 + bc);
        __syncthreads();
        As[ac + 0][ar] = a0.x; As[ac + 1][ar] = a0.y;
        As[ac + 2][ar] = a0.z; As[ac + 3][ar] = a0.w;
        As[ac + 0][ar + 64] = a1.x; As[ac + 1][ar + 64] = a1.y;
        As[ac + 2][ar + 64] = a1.z; As[ac + 3][ar + 64] = a1.w;
        *(float4*)&Bs[br][bc]     = b0;
        *(float4*)&Bs[br + 8][bc] = b1;
        __syncthreads();
        #pragma unroll
        for (int kk = 0; kk < 16; ++kk) {
            float a[8], bb[8];
            *(float4*)&a[0]  = *(const float4*)&As[kk][tm * 8];
            *(float4*)&a[4]  = *(const float4*)&As[kk][tm * 8 + 4];
            *(float4*)&bb[0] = *(const float4*)&Bs[kk][tn * 8];
            *(float4*)&bb[4] = *(const float4*)&Bs[kk][tn * 8 + 4];
            #pragma unroll
            for (int i = 0; i < 8; ++i)
                #pragma unroll
                for (int jx = 0; jx < 8; ++jx)
                    acc[i][jx] = fmaf(a[i], bb[jx], acc[i][jx]);
        }
    }

    #pragma unroll
    for (int i = 0; i < 8; ++i) {
        float* crow = C + (M0 + tm * 8 + i) * 512 + N0 + tn * 8;
        floatx4 o0, o1;
        o0.x = acc[i][0] + bv[0]; o0.y = acc[i][1] + bv[1];
        o0.z = acc[i][2] + bv[2]; o0.w = acc[i][3] + bv[3];
        o1.x = acc[i][4] + bv[4]; o1.y = acc[i][5] + bv[5];
        o1.z = acc[i][6] + bv[6]; o1.w = acc[i][7] + bv[7];
        __builtin_nontemporal_store(o0, (floatx4*)crow);
        __builtin_nontemporal_store(o1, (floatx4*)crow + 1);
    }
}

// ---------------------------------------------------------------------------
// Kernel 2: the scan.
// ---------------------------------------------------------------------------
__global__ __launch_bounds__(256, 1) void rnn_scan(
    const float* __restrict__ whh,          // [512, 512]
    float* __restrict__ out,                // [64,1024,512]; xp, overwritten with h
    unsigned long long* __restrict__ hbuf)  // [2][64][512] 8B {val,tag} packets
{
    __shared__ float hs[4][512];        // h_{t-1}, partitioned per half-wave (8 KB)
    __shared__ float red[2][8][4][32];  // partials, parity double-buffered (8 KB)

    const int tid = threadIdx.x;
    const int b = blockIdx.x;
    const int r = b & 15;            // row group 0..15 -> batch rows 4r..4r+3
    const int s = b >> 4;            // col slice 0..15 -> cols 32s..32s+31
    const int j = tid & 31;
    const int kq = tid >> 5;         // 0..7 (half-wave id)
    const int kbase = kq * 64;
    const int col = s * 32 + j;      // FMA output column
    const int row0 = r * 4;
    const int colp = kbase + 2 * j;  // cols this lane polls & stages (own k-slice)

    // One-time: weight slice into registers. 64 floats/thread.
    float wreg[64];
    #pragma unroll
    for (int kk = 0; kk < 64; ++kk)
        wreg[kk] = whh[(size_t)(kbase + kk) * RNN_F + col];

    const int orow = kq & 3;         // finalize row for tid<128 (waves 0-1)
    const int srow = j & 3;          // sentinel row this lane spins on

    #pragma unroll 1
    for (int t = 0; t < RNN_T; ++t) {
        if (t > 0) {
            const unsigned long long* src = hbuf +
                (size_t)((t + 1) & 1) * (RNN_B * RNN_F) +
                (size_t)row0 * RNN_F + colp;
            const unsigned tagw = (unsigned)(t - 1);

            // Phase 1: sentinel spin -- ONE load per lane (8x less poll
            // traffic than polling all 8). Pure filter; no correctness role.
            {
                const unsigned long long* sp = src + (size_t)srow * RNN_F;
                for (;;) {
                    unsigned long long e = __hip_atomic_load(sp,
                        __ATOMIC_RELAXED, __HIP_MEMORY_SCOPE_AGENT);
                    if ((unsigned)(e >> 32) == tagw) break;
                    __builtin_amdgcn_s_sleep(1);
                }
            }

            // Phase 2: full verify loop over all 8 packets (carries
            // correctness; typically passes on the first iteration).
            unsigned long long e0a, e0b, e1a, e1b, e2a, e2b, e3a, e3b;
            for (;;) {
                e0a = __hip_atomic_load(src + 0 * RNN_F + 0, __ATOMIC_RELAXED, __HIP_MEMORY_SCOPE_AGENT);
                e0b = __hip_atomic_load(src + 0 * RNN_F + 1, __ATOMIC_RELAXED, __HIP_MEMORY_SCOPE_AGENT);
                e1a = __hip_atomic_load(src + 1 * RNN_F + 0, __ATOMIC_RELAXED, __HIP_MEMORY_SCOPE_AGENT);
                e1b = __hip_atomic_load(src + 1 * RNN_F + 1, __ATOMIC_RELAXED, __HIP_MEMORY_SCOPE_AGENT);
                e2a = __hip_atomic_load(src + 2 * RNN_F + 0, __ATOMIC_RELAXED, __HIP_MEMORY_SCOPE_AGENT);
                e2b = __hip_atomic_load(src + 2 * RNN_F + 1, __ATOMIC_RELAXED, __HIP_MEMORY_SCOPE_AGENT);
                e3a = __hip_atomic_load(src + 3 * RNN_F + 0, __ATOMIC_RELAXED, __HIP_MEMORY_SCOPE_AGENT);
                e3b = __hip_atomic_load(src + 3 * RNN_F + 1, __ATOMIC_RELAXED, __HIP_MEMORY_SCOPE_AGENT);
                unsigned bad = ((unsigned)(e0a >> 32) ^ tagw) | ((unsigned)(e0b >> 32) ^ tagw)
                             | ((unsigned)(e1a >> 32) ^ tagw) | ((unsigned)(e1b >> 32) ^ tagw)
                             | ((unsigned)(e2a >> 32) ^ tagw) | ((unsigned)(e2b >> 32) ^ tagw)
                             | ((unsigned)(e3a >> 32) ^ tagw) | ((unsigned)(e3b >> 32) ^ tagw);
                if (bad == 0u) break;
                __builtin_amdgcn_s_sleep(1);
            }
            // Stage into MY half-wave's hs slice. Intra-wave lockstep + DS
            // in-order per wave + compiler lgkmcnt make this barrier-free:
            // the only readers are lanes of this same half-wave.
            *(unsigned long long*)&hs[0][colp] = (e0a & 0xFFFFFFFFull) | (e0b << 32);
            *(unsigned long long*)&hs[1][colp] = (e1a & 0xFFFFFFFFull) | (e1b << 32);
            *(unsigned long long*)&hs[2][colp] = (e2a & 0xFFFFFFFFull) | (e2b << 32);
            *(unsigned long long*)&hs[3][colp] = (e3a & 0xFFFFFFFFull) | (e3b << 32);
        }

        // xp load AFTER the poll, NON-TEMPORAL (read-once stream; must not
        // evict hbuf packets from MALL). Consumed in finalize after barrier.
        float xpv = 0.f;
        if (tid < 128)
            xpv = __builtin_nontemporal_load(
                out + ((size_t)(row0 + orow) * RNN_T + t) * RNN_F + col);

        float acc0 = 0.f, acc1 = 0.f, acc2 = 0.f, acc3 = 0.f;
        if (t > 0) {
            #pragma unroll
            for (int kk = 0; kk < 64; kk += 4) {
                float4 h0 = *(const float4*)&hs[0][kbase + kk];
                float4 h1 = *(const float4*)&hs[1][kbase + kk];
                float4 h2 = *(const float4*)&hs[2][kbase + kk];
                float4 h3 = *(const float4*)&hs[3][kbase + kk];
                acc0 = fmaf(h0.x, wreg[kk+0], acc0);
                acc0 = fmaf(h0.y, wreg[kk+1], acc0);
                acc0 = fmaf(h0.z, wreg[kk+2], acc0);
                acc0 = fmaf(h0.w, wreg[kk+3], acc0);
                acc1 = fmaf(h1.x, wreg[kk+0], acc1);
                acc1 = fmaf(h1.y, wreg[kk+1], acc1);
                acc1 = fmaf(h1.z, wreg[kk+2], acc1);
                acc1 = fmaf(h1.w, wreg[kk+3], acc1);
                acc2 = fmaf(h2.x, wreg[kk+0], acc2);
                acc2 = fmaf(h2.y, wreg[kk+1], acc2);
                acc2 = fmaf(h2.z, wreg[kk+2], acc2);
                acc2 = fmaf(h2.w, wreg[kk+3], acc2);
                acc3 = fmaf(h3.x, wreg[kk+0], acc3);
                acc3 = fmaf(h3.y, wreg[kk+1], acc3);
                acc3 = fmaf(h3.z, wreg[kk+2], acc3);
                acc3 = fmaf(h3.w, wreg[kk+3], acc3);
            }
        }
        const int par = t & 1;
        red[par][kq][0][j] = acc0;
        red[par][kq][1][j] = acc1;
        red[par][kq][2][j] = acc2;
        red[par][kq][3][j] = acc3;
        __syncthreads();   // the ONE barrier per step (gates red reads & reuse)

        // Finalize: waves 0-1, one output each. Fire-and-forget packet store
        // first (cross-block critical path), then NON-TEMPORAL out store.
        if (tid < 128) {
            float sum = 0.f;
            #pragma unroll
            for (int q = 0; q < 8; ++q) sum += red[par][q][orow][j];
            float v = tanhf(xpv + sum);
            unsigned long long* hb = hbuf + (size_t)par * (RNN_B * RNN_F);
            __hip_atomic_store(hb + (size_t)(row0 + orow) * RNN_F + col,
                               ((unsigned long long)(unsigned)t << 32) | __float_as_uint(v),
                               __ATOMIC_RELAXED, __HIP_MEMORY_SCOPE_AGENT);
            __builtin_nontemporal_store(v,
                out + ((size_t)(row0 + orow) * RNN_T + t) * RNN_F + col);
        }
        // Waves 2-3 fall straight through to the next step's poll; red reuse
        // at t+1 targets the other parity, reuse at t+2 is ordered behind this
        // finalize via the packet-poll chain (see header).
    }
}

extern "C" void kernel_launch(void* const* d_in, const int* in_sizes, int n_in,
                              void* d_out, int out_size, void* d_ws, size_t ws_size,
                              hipStream_t stream) {
    const float* X    = (const float*)d_in[0];  // [64,1024,512]
    const float* Wih  = (const float*)d_in[1];  // [512,512]
    const float* Whh  = (const float*)d_in[2];  // [512,512]
    const float* bias = (const float*)d_in[3];  // [512]
    float* out = (float*)d_out;                 // [64,1024,512]

    unsigned long long* hbuf = (unsigned long long*)d_ws;  // 2*64*512*8B = 512 KB

    // Tag field of every packet -> 0xFFFFFFFF (matches no step).
    hipMemsetAsync(hbuf, 0xFF, (size_t)2 * RNN_B * RNN_F * sizeof(unsigned long long),
                   stream);

    xproj_gemm<<<dim3(2048), dim3(256), 0, stream>>>(X, Wih, bias, out);
    rnn_scan<<<dim3(256), dim3(256), 0, stream>>>(Whh, out, hbuf);
}

// Round 7
// 3985.729 us; speedup vs baseline: 1.0777x; 1.0777x over previous
//
#include <hip/hip_runtime.h>

// Problem: B=64, T=1024, D=512, F=512, all fp32.
// out[b,t,:] = h_t = tanh(x_t @ W_ih + bias + h_{t-1} @ W_hh)
//
// K1: x_proj GEMM [65536,512]@[512,512]+bias -> d_out (xp buffer, overwritten
//     in-place by the scan; each slot read exactly once before overwrite).
// K2: persistent scan -- THIS ROUND: batch rows are INDEPENDENT, so the minimum
//     coupling is set by W_hh (1MB) vs the 512KB/CU register file: a 4-block
//     group owns ONE row (256KB of W per block in VGPRs). 64 groups x 4 = 256
//     blocks. vs R6 (16-block groups): fan-in 16->4 producers, poll 8->4
//     packets/lane, reduction depth 8->2, no cross-group coupling at all.
//     Exchange stays 8-byte self-validating packets {lo32=val, hi32=step tag}
//     via relaxed agent-scope 8B atomics (R2-verified MALL coherence point).
//     R6 lesson: TCC FETCH/WRITE = L2<->fabric traffic (MALL absorbs it);
//     packets were never HBM-evicted, so per-hop latency is already floor ->
//     attack the CHAIN STRUCTURE instead. Poll sleep dropped (traffic now
//     ~0.5TB/s, 25x under R4's congestion level).
//     Block: row = bid&63, member m = bid>>6 (64-apart -> same XCD mod 8),
//     cols [m*128,+128). Threads: c=tid&127, kh=tid>>7; wreg[256] = W[kh-half].
//     Staging: wave w (k-half w>>1) redundantly polls+stages ITS OWN 256-value
//     k-slice (4 packets/lane) into hs[par][w][*] -- readers are the same wave
//     only -> barrier-free (R6-verified same-wave DS ordering).
//     Ordering ledger (re-derived for 4-block groups):
//       hs[par] overwrite @t+2 <= owner polls@t+2 <= all members' barrier@t+1
//         <= every member wave's poll@t+1 passed <= my FMA reads@t done.
//       red parity-double-buffered (members 0/1 kh=1 waves poll purely-remote
//         cols, so single-buffer red would race reader@t vs writer@t+1).
//       Packet slots monotonically tagged; exact-match vs t-1; stale = t-3 or
//       0xFFFFFFFF memset -> no false positives. Wait graph = DAG over
//       (block,t); VGPR ~300 -> 1 block/CU -> all 256 co-resident -> no
//       deadlock. 1 __syncthreads per step.

#define RNN_B 64
#define RNN_T 1024
#define RNN_D 512
#define RNN_F 512

// ---------------------------------------------------------------------------
// Kernel 1: x_proj = X @ W_ih + bias.  M=65536, N=512, K=512.
// (reverted to plain stores; R6 showed non-temporal neutral)
// ---------------------------------------------------------------------------
__global__ __launch_bounds__(256) void xproj_gemm(
    const float* __restrict__ A,     // [65536, 512]
    const float* __restrict__ W,     // [512, 512]
    const float* __restrict__ bias,  // [512]
    float* __restrict__ C)           // [65536, 512]
{
    __shared__ float As[16][132];
    __shared__ float Bs[16][132];

    const int tid = threadIdx.x;
    const int bid = blockIdx.x;
    const int mt = bid >> 2;
    const int nt = bid & 3;
    const size_t M0 = (size_t)mt * 128;
    const int N0 = nt * 128;

    const int tm = tid >> 4;
    const int tn = tid & 15;

    const int ar = tid >> 2;
    const int ac = (tid & 3) * 4;
    const int br = tid >> 5;
    const int bc = (tid & 31) * 4;

    float acc[8][8];
    #pragma unroll
    for (int i = 0; i < 8; ++i)
        #pragma unroll
        for (int jx = 0; jx < 8; ++jx) acc[i][jx] = 0.f;

    float bv[8];
    #pragma unroll
    for (int i = 0; i < 8; ++i) bv[i] = bias[N0 + tn * 8 + i];

    for (int k0 = 0; k0 < 512; k0 += 16) {
        float4 a0 = *(const float4*)(A + (M0 + ar) * 512 + k0 + ac);
        float4 a1 = *(const float4*)(A + (M0 + ar + 64) * 512 + k0 + ac);
        float4 b0 = *(const float4*)(W + (size_t)(k0 + br) * 512 + N0 + bc);
        float4 b1 = *(const float4*)(W + (size_t)(k0 + br + 8) * 512 + N0 + bc);
        __syncthreads();
        As[ac + 0][ar] = a0.x; As[ac + 1][ar] = a0.y;
        As[ac + 2][ar] = a0.z; As[ac + 3][ar] = a0.w;
        As[ac + 0][ar + 64] = a1.x; As[ac + 1][ar + 64] = a1.y;
        As[ac + 2][ar + 64] = a1.z; As[ac + 3][ar + 64] = a1.w;
        *(float4*)&Bs[br][bc]     = b0;
        *(float4*)&Bs[br + 8][bc] = b1;
        __syncthreads();
        #pragma unroll
        for (int kk = 0; kk < 16; ++kk) {
            float a[8], bb[8];
            *(float4*)&a[0]  = *(const float4*)&As[kk][tm * 8];
            *(float4*)&a[4]  = *(const float4*)&As[kk][tm * 8 + 4];
            *(float4*)&bb[0] = *(const float4*)&Bs[kk][tn * 8];
            *(float4*)&bb[4] = *(const float4*)&Bs[kk][tn * 8 + 4];
            #pragma unroll
            for (int i = 0; i < 8; ++i)
                #pragma unroll
                for (int jx = 0; jx < 8; ++jx)
                    acc[i][jx] = fmaf(a[i], bb[jx], acc[i][jx]);
        }
    }

    #pragma unroll
    for (int i = 0; i < 8; ++i) {
        float* crow = C + (M0 + tm * 8 + i) * 512 + N0 + tn * 8;
        float4 o0, o1;
        o0.x = acc[i][0] + bv[0]; o0.y = acc[i][1] + bv[1];
        o0.z = acc[i][2] + bv[2]; o0.w = acc[i][3] + bv[3];
        o1.x = acc[i][4] + bv[4]; o1.y = acc[i][5] + bv[5];
        o1.z = acc[i][6] + bv[6]; o1.w = acc[i][7] + bv[7];
        *(float4*)crow = o0;
        *((float4*)crow + 1) = o1;
    }
}

// ---------------------------------------------------------------------------
// Kernel 2: the scan.  64 groups (1 batch row each) x 4 member blocks.
// ---------------------------------------------------------------------------
__global__ __launch_bounds__(256, 1) void rnn_scan(
    const float* __restrict__ whh,          // [512, 512]
    float* __restrict__ out,                // [64,1024,512]; xp, overwritten with h
    unsigned long long* __restrict__ hbuf)  // [2][64][512] 8B {val,tag} packets
{
    __shared__ float hs[2][4][256];     // [parity][wave][k-slice]   8 KB
    __shared__ float red[2][128];       // [parity][c]               1 KB

    const int tid = threadIdx.x;
    const int w   = tid >> 6;            // wave 0..3
    const int l   = tid & 63;            // lane
    const int c   = tid & 127;           // col within block's slice
    const int kh  = tid >> 7;            // k-half this thread accumulates
    const int row  = blockIdx.x & 63;    // group = batch row
    const int m    = blockIdx.x >> 6;    // member 0..3
    const int col  = m * 128 + c;        // output column
    const int wkh  = w >> 1;             // this wave's k-half
    const int pcol = wkh * 256 + 4 * l;  // first of 4 cols this lane polls

    // Weight slice into registers: wreg[i] = W[kh*256+i][col].  256 VGPRs.
    float wreg[256];
    #pragma unroll
    for (int i = 0; i < 256; ++i)
        wreg[i] = whh[(size_t)(kh * 256 + i) * RNN_F + col];

    // h_{-1} = 0 (each wave inits its own slice; barrier covers cross-wave).
    #pragma unroll
    for (int i = 0; i < 4; ++i) hs[0][w][4 * l + i] = 0.f;
    __syncthreads();

    const float* xrow = out + (size_t)row * RNN_T * RNN_F;

    #pragma unroll 1
    for (int t = 0; t < RNN_T; ++t) {
        const int par = t & 1;

        if (t > 0) {
            // Poll MY wave's 4 packets of h_{t-1} (parity (t-1)&1). No sleep:
            // poll traffic is ~0.5 TB/s total, latency matters more.
            const unsigned long long* src = hbuf +
                (size_t)((t + 1) & 1) * (RNN_B * RNN_F) +
                (size_t)row * RNN_F + pcol;
            const unsigned tagw = (unsigned)(t - 1);
            unsigned long long e0, e1, e2, e3;
            for (;;) {
                e0 = __hip_atomic_load(src + 0, __ATOMIC_RELAXED, __HIP_MEMORY_SCOPE_AGENT);
                e1 = __hip_atomic_load(src + 1, __ATOMIC_RELAXED, __HIP_MEMORY_SCOPE_AGENT);
                e2 = __hip_atomic_load(src + 2, __ATOMIC_RELAXED, __HIP_MEMORY_SCOPE_AGENT);
                e3 = __hip_atomic_load(src + 3, __ATOMIC_RELAXED, __HIP_MEMORY_SCOPE_AGENT);
                unsigned bad = ((unsigned)(e0 >> 32) ^ tagw)
                             | ((unsigned)(e1 >> 32) ^ tagw)
                             | ((unsigned)(e2 >> 32) ^ tagw)
                             | ((unsigned)(e3 >> 32) ^ tagw);
                if (bad == 0u) break;
            }
            // Stage into MY wave's hs slice (readers = this wave only ->
            // same-wave DS ordering, no barrier; R6-verified pattern).
            float4 f4;
            f4.x = __uint_as_float((unsigned)e0);
            f4.y = __uint_as_float((unsigned)e1);
            f4.z = __uint_as_float((unsigned)e2);
            f4.w = __uint_as_float((unsigned)e3);
            *(float4*)&hs[par][w][4 * l] = f4;
        }

        // xp prefetch (kh=0 threads own the outputs); consumed after the
        // barrier -> latency hidden under the FMA phase.
        float xpv = 0.f;
        if (kh == 0)
            xpv = xrow[(size_t)t * RNN_F + col];

        // FMA: 256 k-values, broadcast LDS reads (all lanes same address).
        float a0 = 0.f, a1 = 0.f, a2 = 0.f, a3 = 0.f;
        #pragma unroll
        for (int kk = 0; kk < 256; kk += 4) {
            float4 h4 = *(const float4*)&hs[par][w][kk];
            a0 = fmaf(h4.x, wreg[kk + 0], a0);
            a1 = fmaf(h4.y, wreg[kk + 1], a1);
            a2 = fmaf(h4.z, wreg[kk + 2], a2);
            a3 = fmaf(h4.w, wreg[kk + 3], a3);
        }
        float part = (a0 + a1) + (a2 + a3);

        if (kh == 1) red[par][c] = part;
        __syncthreads();   // the ONE barrier per step

        // Finalize: kh=0 threads. Fire-and-forget packet store first (the
        // cross-block critical path), then the out store.
        if (kh == 0) {
            float v = tanhf(xpv + part + red[par][c]);
            __hip_atomic_store(
                hbuf + (size_t)par * (RNN_B * RNN_F) + (size_t)row * RNN_F + col,
                ((unsigned long long)(unsigned)t << 32) | __float_as_uint(v),
                __ATOMIC_RELAXED, __HIP_MEMORY_SCOPE_AGENT);
            out[((size_t)row * RNN_T + t) * RNN_F + col] = v;
        }
        // No second barrier: hs/red reuse is ordered via the packet-poll
        // chain (see header ledger).
    }
}

extern "C" void kernel_launch(void* const* d_in, const int* in_sizes, int n_in,
                              void* d_out, int out_size, void* d_ws, size_t ws_size,
                              hipStream_t stream) {
    const float* X    = (const float*)d_in[0];  // [64,1024,512]
    const float* Wih  = (const float*)d_in[1];  // [512,512]
    const float* Whh  = (const float*)d_in[2];  // [512,512]
    const float* bias = (const float*)d_in[3];  // [512]
    float* out = (float*)d_out;                 // [64,1024,512]

    unsigned long long* hbuf = (unsigned long long*)d_ws;  // 2*64*512*8B = 512 KB

    // Tag field of every packet -> 0xFFFFFFFF (matches no step).
    hipMemsetAsync(hbuf, 0xFF, (size_t)2 * RNN_B * RNN_F * sizeof(unsigned long long),
                   stream);

    xproj_gemm<<<dim3(2048), dim3(256), 0, stream>>>(X, Wih, bias, out);
    rnn_scan<<<dim3(256), dim3(256), 0, stream>>>(Whh, out, hbuf);
}

// Round 8
// 3008.944 us; speedup vs baseline: 1.4275x; 1.3246x over previous
//
#include <hip/hip_runtime.h>

// Problem: B=64, T=1024, D=512, F=512, all fp32.
// out[b,t,:] = h_t = tanh(x_t @ W_ih + bias + h_{t-1} @ W_hh)
//
// K1: x_proj GEMM [65536,512]@[512,512]+bias -> d_out (xp buffer, overwritten
//     in-place by the scan; each slot read exactly once before overwrite).
// K2: persistent scan -- THIS ROUND: wave-autonomous units + W pinned on-chip.
//     R7 lesson (VGPR_Count=140): the compiler REMATERIALIZED wreg[256] from
//     global inside the t-loop -> 256KB of W streamed from L2 per block per
//     step (~1.9us/step) -- the real R7 bottleneck. Fix: per-thread W slice
//     split 128 floats in VGPR (wr[128], ~190 total VGPR -> allocatable, like
//     R4's held 100) + 128 floats in a THREAD-PRIVATE LDS slice Wl[tid][132]
//     (135KB, padded stride, self-read only -> no sync, full-BW b128 reads).
//     Zero W traffic in the loop.
//     Sync structure: each WAVE is an independent unit owning 32 cols of one
//     row (4 waves x 4 members x 64 rows = 1024 units). Per step, a wave
//     redundantly polls+stages ALL 512 h-packets of its row (8/lane, stride-64
//     cols -> conflict-free b32 LDS stores) into its OWN hs[par][w] slice --
//     readers are the same wave only (R4/R6-verified same-wave DS ordering).
//     ks-pair reduction via __shfl_xor(part,32). ZERO __syncthreads per step.
//     Exchange: 8B self-validating packets {lo=val, hi=step tag}, relaxed
//     agent-scope atomics (R2-verified). Ordering ledger: every wave polls all
//     row-cols each step -> skew<=1 between any two waves of a row -> hbuf
//     parity slot (tag t) overwritten at t+2 only after ALL row waves stored
//     t+1, which requires each passed poll(t) -> all tag-t reads done. hs
//     parity-double-buffered, wave-local. Stale tags = t-3 or 0xFFFFFFFF ->
//     exact-match poll never false-positives. Wait graph = DAG over (unit,t);
//     LDS 148KB -> 1 block/CU -> all 256 blocks resident -> no deadlock.

#define RNN_B 64
#define RNN_T 1024
#define RNN_D 512
#define RNN_F 512

// ---------------------------------------------------------------------------
// Kernel 1: x_proj = X @ W_ih + bias.  M=65536, N=512, K=512.  (unchanged)
// ---------------------------------------------------------------------------
__global__ __launch_bounds__(256) void xproj_gemm(
    const float* __restrict__ A,     // [65536, 512]
    const float* __restrict__ W,     // [512, 512]
    const float* __restrict__ bias,  // [512]
    float* __restrict__ C)           // [65536, 512]
{
    __shared__ float As[16][132];
    __shared__ float Bs[16][132];

    const int tid = threadIdx.x;
    const int bid = blockIdx.x;
    const int mt = bid >> 2;
    const int nt = bid & 3;
    const size_t M0 = (size_t)mt * 128;
    const int N0 = nt * 128;

    const int tm = tid >> 4;
    const int tn = tid & 15;

    const int ar = tid >> 2;
    const int ac = (tid & 3) * 4;
    const int br = tid >> 5;
    const int bc = (tid & 31) * 4;

    float acc[8][8];
    #pragma unroll
    for (int i = 0; i < 8; ++i)
        #pragma unroll
        for (int jx = 0; jx < 8; ++jx) acc[i][jx] = 0.f;

    float bv[8];
    #pragma unroll
    for (int i = 0; i < 8; ++i) bv[i] = bias[N0 + tn * 8 + i];

    for (int k0 = 0; k0 < 512; k0 += 16) {
        float4 a0 = *(const float4*)(A + (M0 + ar) * 512 + k0 + ac);
        float4 a1 = *(const float4*)(A + (M0 + ar + 64) * 512 + k0 + ac);
        float4 b0 = *(const float4*)(W + (size_t)(k0 + br) * 512 + N0 + bc);
        float4 b1 = *(const float4*)(W + (size_t)(k0 + br + 8) * 512 + N0 + bc);
        __syncthreads();
        As[ac + 0][ar] = a0.x; As[ac + 1][ar] = a0.y;
        As[ac + 2][ar] = a0.z; As[ac + 3][ar] = a0.w;
        As[ac + 0][ar + 64] = a1.x; As[ac + 1][ar + 64] = a1.y;
        As[ac + 2][ar + 64] = a1.z; As[ac + 3][ar + 64] = a1.w;
        *(float4*)&Bs[br][bc]     = b0;
        *(float4*)&Bs[br + 8][bc] = b1;
        __syncthreads();
        #pragma unroll
        for (int kk = 0; kk < 16; ++kk) {
            float a[8], bb[8];
            *(float4*)&a[0]  = *(const float4*)&As[kk][tm * 8];
            *(float4*)&a[4]  = *(const float4*)&As[kk][tm * 8 + 4];
            *(float4*)&bb[0] = *(const float4*)&Bs[kk][tn * 8];
            *(float4*)&bb[4] = *(const float4*)&Bs[kk][tn * 8 + 4];
            #pragma unroll
            for (int i = 0; i < 8; ++i)
                #pragma unroll
                for (int jx = 0; jx < 8; ++jx)
                    acc[i][jx] = fmaf(a[i], bb[jx], acc[i][jx]);
        }
    }

    #pragma unroll
    for (int i = 0; i < 8; ++i) {
        float* crow = C + (M0 + tm * 8 + i) * 512 + N0 + tn * 8;
        float4 o0, o1;
        o0.x = acc[i][0] + bv[0]; o0.y = acc[i][1] + bv[1];
        o0.z = acc[i][2] + bv[2]; o0.w = acc[i][3] + bv[3];
        o1.x = acc[i][4] + bv[4]; o1.y = acc[i][5] + bv[5];
        o1.z = acc[i][6] + bv[6]; o1.w = acc[i][7] + bv[7];
        *(float4*)crow = o0;
        *((float4*)crow + 1) = o1;
    }
}

// ---------------------------------------------------------------------------
// Kernel 2: the scan.  1024 wave-units: (row 0..63) x (member 0..3) x (wave 0..3).
// ---------------------------------------------------------------------------
__global__ __launch_bounds__(256, 1) void rnn_scan(
    const float* __restrict__ whh,          // [512, 512]
    float* __restrict__ out,                // [64,1024,512]; xp, overwritten with h
    unsigned long long* __restrict__ hbuf)  // [2][64][512] 8B {val,tag} packets
{
    __shared__ float Wl[256][132];      // per-thread private W-hi slice, 135168 B
    __shared__ float hs[2][4][512];     // per-wave h staging, parity dbuf, 16384 B

    const int tid = threadIdx.x;
    const int w   = tid >> 6;            // wave 0..3
    const int l   = tid & 63;            // lane
    const int ks  = l >> 5;              // k-segment 0/1 (lane halves)
    const int c   = (w << 5) + (l & 31); // col within block slice 0..127
    const int row = blockIdx.x & 63;     // group = batch row
    const int m   = blockIdx.x >> 6;     // member 0..3
    const int col = (m << 7) + c;        // output column
    const int hsb = ks << 8;             // this lane's k-base in hs (0 or 256)

    // W for k in [256ks, 256ks+128) -> VGPR; [256ks+128, 256ks+256) -> LDS.
    // Wl[tid] is written and read ONLY by this thread (manual on-chip spill
    // storage) -> no barrier ever needed for it.
    float wr[128];
    #pragma unroll
    for (int i = 0; i < 128; ++i)
        wr[i] = whh[(size_t)(hsb + i) * RNN_F + col];
    #pragma unroll
    for (int i = 0; i < 128; ++i)
        Wl[tid][i] = whh[(size_t)(hsb + 128 + i) * RNN_F + col];

    float* orow = out + (size_t)row * RNN_T * RNN_F;

    #pragma unroll 1
    for (int t = 0; t < RNN_T; ++t) {
        const int par = t & 1;

        if (t > 0) {
            // Poll all 512 cols of h_{t-1} for my row: lane stages cols
            // {l + 64i, i=0..7} (stride-64 -> conflict-free LDS, coalesced
            // global). Sentinel first (1 load), then 8-load verify loop.
            const unsigned long long* src = hbuf +
                (size_t)((t + 1) & 1) * (RNN_B * RNN_F) + (size_t)row * RNN_F;
            const unsigned tagw = (unsigned)(t - 1);
            {
                const unsigned long long* sp = src + l + ((l & 7) << 6);
                for (;;) {
                    unsigned long long e = __hip_atomic_load(sp,
                        __ATOMIC_RELAXED, __HIP_MEMORY_SCOPE_AGENT);
                    if ((unsigned)(e >> 32) == tagw) break;
                }
            }
            unsigned long long e0, e1, e2, e3, e4, e5, e6, e7;
            for (;;) {
                e0 = __hip_atomic_load(src + l + 0 * 64, __ATOMIC_RELAXED, __HIP_MEMORY_SCOPE_AGENT);
                e1 = __hip_atomic_load(src + l + 1 * 64, __ATOMIC_RELAXED, __HIP_MEMORY_SCOPE_AGENT);
                e2 = __hip_atomic_load(src + l + 2 * 64, __ATOMIC_RELAXED, __HIP_MEMORY_SCOPE_AGENT);
                e3 = __hip_atomic_load(src + l + 3 * 64, __ATOMIC_RELAXED, __HIP_MEMORY_SCOPE_AGENT);
                e4 = __hip_atomic_load(src + l + 4 * 64, __ATOMIC_RELAXED, __HIP_MEMORY_SCOPE_AGENT);
                e5 = __hip_atomic_load(src + l + 5 * 64, __ATOMIC_RELAXED, __HIP_MEMORY_SCOPE_AGENT);
                e6 = __hip_atomic_load(src + l + 6 * 64, __ATOMIC_RELAXED, __HIP_MEMORY_SCOPE_AGENT);
                e7 = __hip_atomic_load(src + l + 7 * 64, __ATOMIC_RELAXED, __HIP_MEMORY_SCOPE_AGENT);
                unsigned bad = ((unsigned)(e0 >> 32) ^ tagw) | ((unsigned)(e1 >> 32) ^ tagw)
                             | ((unsigned)(e2 >> 32) ^ tagw) | ((unsigned)(e3 >> 32) ^ tagw)
                             | ((unsigned)(e4 >> 32) ^ tagw) | ((unsigned)(e5 >> 32) ^ tagw)
                             | ((unsigned)(e6 >> 32) ^ tagw) | ((unsigned)(e7 >> 32) ^ tagw);
                if (bad == 0u) break;
            }
            // Stage into MY wave's slice; readers = this wave only -> no barrier.
            hs[par][w][l + 0 * 64] = __uint_as_float((unsigned)e0);
            hs[par][w][l + 1 * 64] = __uint_as_float((unsigned)e1);
            hs[par][w][l + 2 * 64] = __uint_as_float((unsigned)e2);
            hs[par][w][l + 3 * 64] = __uint_as_float((unsigned)e3);
            hs[par][w][l + 4 * 64] = __uint_as_float((unsigned)e4);
            hs[par][w][l + 5 * 64] = __uint_as_float((unsigned)e5);
            hs[par][w][l + 6 * 64] = __uint_as_float((unsigned)e6);
            hs[par][w][l + 7 * 64] = __uint_as_float((unsigned)e7);
        }

        // xp load after the poll (hides under FMA; R4-verified placement).
        float xpv = 0.f;
        if (l < 32)
            xpv = orow[(size_t)t * RNN_F + col];

        float a0 = 0.f, a1 = 0.f, a2 = 0.f, a3 = 0.f;
        if (t > 0) {
            #pragma unroll
            for (int kk = 0; kk < 128; kk += 4) {   // k-lo from VGPR W
                float4 h4 = *(const float4*)&hs[par][w][hsb + kk];
                a0 = fmaf(h4.x, wr[kk + 0], a0);
                a1 = fmaf(h4.y, wr[kk + 1], a1);
                a2 = fmaf(h4.z, wr[kk + 2], a2);
                a3 = fmaf(h4.w, wr[kk + 3], a3);
            }
            #pragma unroll
            for (int kk = 0; kk < 128; kk += 4) {   // k-hi from LDS W
                float4 h4 = *(const float4*)&hs[par][w][hsb + 128 + kk];
                float4 w4 = *(const float4*)&Wl[tid][kk];
                a0 = fmaf(h4.x, w4.x, a0);
                a1 = fmaf(h4.y, w4.y, a1);
                a2 = fmaf(h4.z, w4.z, a2);
                a3 = fmaf(h4.w, w4.w, a3);
            }
        }
        float part = (a0 + a1) + (a2 + a3);
        part += __shfl_xor(part, 32);   // ks-pair reduce, in-register

        if (l < 32) {
            float v = tanhf(xpv + part);
            // Fire-and-forget packet store first (cross-unit critical path).
            __hip_atomic_store(
                hbuf + (size_t)par * (RNN_B * RNN_F) + (size_t)row * RNN_F + col,
                ((unsigned long long)(unsigned)t << 32) | __float_as_uint(v),
                __ATOMIC_RELAXED, __HIP_MEMORY_SCOPE_AGENT);
            orow[(size_t)t * RNN_F + col] = v;
        }
        // No barrier: hs is wave-local (parity dbuf); hbuf reuse ordered by
        // the all-cols poll chain (see header ledger).
    }
}

extern "C" void kernel_launch(void* const* d_in, const int* in_sizes, int n_in,
                              void* d_out, int out_size, void* d_ws, size_t ws_size,
                              hipStream_t stream) {
    const float* X    = (const float*)d_in[0];  // [64,1024,512]
    const float* Wih  = (const float*)d_in[1];  // [512,512]
    const float* Whh  = (const float*)d_in[2];  // [512,512]
    const float* bias = (const float*)d_in[3];  // [512]
    float* out = (float*)d_out;                 // [64,1024,512]

    unsigned long long* hbuf = (unsigned long long*)d_ws;  // 2*64*512*8B = 512 KB

    // Tag field of every packet -> 0xFFFFFFFF (matches no step).
    hipMemsetAsync(hbuf, 0xFF, (size_t)2 * RNN_B * RNN_F * sizeof(unsigned long long),
                   stream);

    xproj_gemm<<<dim3(2048), dim3(256), 0, stream>>>(X, Wih, bias, out);
    rnn_scan<<<dim3(256), dim3(256), 0, stream>>>(Whh, out, hbuf);
}